// Round 10
// baseline (173.344 us; speedup 1.0000x reference)
//
#include <hip/hip_runtime.h>

#define BS     4096
#define HIDDEN 2048
#define MAXR   16
#define NSLOT  8
#define NMOD   2
#define OUTW   8192
#define ROWS   8

typedef float f4 __attribute__((ext_vector_type(4)));

// ---------------------------------------------------------------------------
// Kernel 1: shrink (byte-identical to r8/r9 — proven clean, ~10 us).
// ---------------------------------------------------------------------------
__global__ __launch_bounds__(256) void lora_shrink(
    const float* __restrict__ x,
    const float* __restrict__ A,
    const int*   __restrict__ sorted_ids,
    const int*   __restrict__ slot_ranks,
    const int*   __restrict__ slot_offsets,
    float*       __restrict__ inter)
{
    __shared__ float red[4 * 4 * ROWS * MAXR];   // 8 KiB (w,g,j,r)

    const int t  = threadIdx.x;
    const int b  = blockIdx.x;
    const int m  = b >> 9;            // 0..1
    const int i0 = (b & 511) * ROWS;  // row base

    int s = 0;
    #pragma unroll
    for (int k = 1; k < NSLOT; ++k) if (i0 >= slot_offsets[k]) s = k;
    const int R = slot_ranks[s];

    int tok[ROWS];
    #pragma unroll
    for (int j = 0; j < ROWS; ++j) tok[j] = sorted_ids[i0 + j];  // uniform

    const int hq = t >> 2;   // 0..63
    const int q  = t & 3;    // r-quad

    f4 acc[ROWS];
    #pragma unroll
    for (int j = 0; j < ROWS; ++j) acc[j] = (f4)(0.f);

    const float* Ap_base = A + (size_t)(m * NSLOT + s) * (HIDDEN * MAXR);

    #pragma unroll 1
    for (int k = 0; k < 8; ++k) {
        f4 xv[ROWS];
        #pragma unroll
        for (int j = 0; j < ROWS; ++j)
            xv[j] = *(const f4*)(x + (size_t)tok[j] * HIDDEN + 256 * k + 4 * hq);
        const float* Ap = Ap_base + 4096 * k + 64 * hq + 4 * q;
        const f4 a0 = *(const f4*)(Ap);
        const f4 a1 = *(const f4*)(Ap + 16);
        const f4 a2 = *(const f4*)(Ap + 32);
        const f4 a3 = *(const f4*)(Ap + 48);
        #pragma unroll
        for (int j = 0; j < ROWS; ++j) {
            const f4 v = xv[j];
            acc[j] += v.x * a0 + v.y * a1 + v.z * a2 + v.w * a3;
        }
    }

    #pragma unroll
    for (int j = 0; j < ROWS; ++j) {
        f4 a = acc[j];
        a.x += __shfl_xor(a.x, 4); a.y += __shfl_xor(a.y, 4);
        a.z += __shfl_xor(a.z, 4); a.w += __shfl_xor(a.w, 4);
        a.x += __shfl_xor(a.x, 8); a.y += __shfl_xor(a.y, 8);
        a.z += __shfl_xor(a.z, 8); a.w += __shfl_xor(a.w, 8);
        acc[j] = a;
    }

    if ((t & 12) == 0) {
        const int w = t >> 6, g = (t >> 4) & 3;
        #pragma unroll
        for (int j = 0; j < ROWS; ++j)
            *(f4*)(red + ((w * 4 + g) * ROWS + j) * MAXR + 4 * q) = acc[j];
    }
    __syncthreads();

    if (t < 128) {
        const int j = t >> 4, r = t & 15;
        float v = 0.f;
        #pragma unroll
        for (int w = 0; w < 4; ++w)
            #pragma unroll
            for (int g = 0; g < 4; ++g)
                v += red[((w * 4 + g) * ROWS + j) * MAXR + r];
        if (r >= R) v = 0.f;
        inter[((size_t)m * BS + (i0 + j)) * MAXR + r] = v;
    }
}

// ---------------------------------------------------------------------------
// Kernel 2: expand — DIAGNOSTIC build. Body is byte-identical to r9, but the
// row loop runs 3x (idempotent: same addresses, same values; the asm memory
// clobber between reps prevents dead-store-elim / cross-rep CSE). Purpose:
// dispatch duration ~3x E rises above the ~155 us harness fills, so this
// kernel's own counters (hbm_gbps, VALUBusy, OccupancyPercent, WRITE_SIZE)
// appear in the rocprof top-5 and decide between store-pattern-limited vs
// instruction-bound vs "expand was never slow".
// ---------------------------------------------------------------------------
__global__ __launch_bounds__(256) void lora_expand(
    const float* __restrict__ inter,
    const float* __restrict__ B,
    const int*   __restrict__ slot_offsets,
    const int*   __restrict__ slot_counts,
    float*       __restrict__ out)
{
    int b = blockIdx.x;
    const int rc = b & 15; b >>= 4;      // row chunk   (16 x 32 rows)
    const int ct = b & 7;  b >>= 3;      // col tile    (8 x 1024 cols)
    const int s  = b & 7;  const int m = b >> 3;
    const int t  = threadIdx.x;

    const int row0   = slot_offsets[s] + rc * 32;
    const int rowEnd = slot_offsets[s] + slot_counts[s];
    const int rend   = min(row0 + 32, rowEnd);

    const int c0 = ct * 1024 + t * 4;
    const float* Bp = B + ((size_t)m * NSLOT + s) * MAXR * OUTW + c0;

    #pragma unroll 1
    for (int rep = 0; rep < 3; ++rep) {
        f4 breg[MAXR];
        #pragma unroll
        for (int rr = 0; rr < MAXR; ++rr)
            breg[rr] = *(const f4*)(Bp + (size_t)rr * OUTW);

        for (int i = row0; i < rend; ++i) {
            const float* ip = inter + ((size_t)m * BS + i) * MAXR;  // uniform
            const f4 w0 = *(const f4*)(ip);
            const f4 w1 = *(const f4*)(ip + 4);
            const f4 w2 = *(const f4*)(ip + 8);
            const f4 w3 = *(const f4*)(ip + 12);
            f4 acc = (f4)(0.f);
            acc += w0.x * breg[0]  + w0.y * breg[1]  + w0.z * breg[2]  + w0.w * breg[3];
            acc += w1.x * breg[4]  + w1.y * breg[5]  + w1.z * breg[6]  + w1.w * breg[7];
            acc += w2.x * breg[8]  + w2.y * breg[9]  + w2.z * breg[10] + w2.w * breg[11];
            acc += w3.x * breg[12] + w3.y * breg[13] + w3.z * breg[14] + w3.w * breg[15];
            *(f4*)(out + (size_t)i * (NMOD * OUTW) + (size_t)m * OUTW + c0) = acc;
        }
        __asm__ volatile("" ::: "memory");   // keep all 3 reps' stores live
    }
}

extern "C" void kernel_launch(void* const* d_in, const int* in_sizes, int n_in,
                              void* d_out, int out_size, void* d_ws, size_t ws_size,
                              hipStream_t stream)
{
    const float* x            = (const float*)d_in[0];
    const float* A            = (const float*)d_in[1];
    const float* B            = (const float*)d_in[2];
    const int*   sorted_ids   = (const int*)d_in[3];
    const int*   slot_counts  = (const int*)d_in[4];
    const int*   slot_ranks   = (const int*)d_in[5];
    const int*   slot_offsets = (const int*)d_in[6];
    float*       out          = (float*)d_out;
    float*       inter        = (float*)d_ws;   // NMOD*BS*MAXR*4 = 512 KiB

    hipLaunchKernelGGL(lora_shrink, dim3(BS / ROWS * NMOD), dim3(256), 0, stream,
                       x, A, sorted_ids, slot_ranks, slot_offsets, inter);
    hipLaunchKernelGGL(lora_expand, dim3(NMOD * NSLOT * 8 * 16), dim3(256), 0, stream,
                       inter, B, slot_offsets, slot_counts, out);
}

// Round 11
// 126.780 us; speedup vs baseline: 1.3673x; 1.3673x over previous
//
#include <hip/hip_runtime.h>

#define BS     4096
#define HIDDEN 2048
#define MAXR   16
#define NSLOT  8
#define NMOD   2
#define OUTW   8192
#define ROWS   8

typedef float f4 __attribute__((ext_vector_type(4)));

// ---------------------------------------------------------------------------
// Kernel 1: shrink — DIAGNOSTIC build. Body byte-identical to r9's shrink,
// wrapped in a 5x repeat (idempotent: every rep recomputes and rewrites the
// same inter values; asm memory clobber stops cross-rep CSE/DSE). 5x lifts
// the dispatch to ~190-200 us, ABOVE the ~157 us harness fills, so shrink's
// own counter row (hbm_gbps / VALUBusy / OccupancyPercent / FETCH_SIZE)
// finally appears in the top-5. r10 proved expand = 44 us (store floor);
// shrink ~40 us is now the entire remaining gap and its limiting pipe is
// unknown — measure before editing further.
// ---------------------------------------------------------------------------
__global__ __launch_bounds__(256) void lora_shrink(
    const float* __restrict__ x,
    const float* __restrict__ A,
    const int*   __restrict__ sorted_ids,
    const int*   __restrict__ slot_ranks,
    const int*   __restrict__ slot_offsets,
    float*       __restrict__ inter)
{
    __shared__ float red[4 * 4 * ROWS * MAXR];   // 8 KiB (w,g,j,r)

    const int t  = threadIdx.x;
    const int b  = blockIdx.x;
    const int m  = b >> 9;            // 0..1
    const int i0 = (b & 511) * ROWS;  // row base

    #pragma unroll 1
    for (int rep = 0; rep < 5; ++rep) {

        int s = 0;
        #pragma unroll
        for (int k = 1; k < NSLOT; ++k) if (i0 >= slot_offsets[k]) s = k;
        const int R = slot_ranks[s];

        int tok[ROWS];
        #pragma unroll
        for (int j = 0; j < ROWS; ++j) tok[j] = sorted_ids[i0 + j];  // uniform

        const int hq = t >> 2;   // 0..63
        const int q  = t & 3;    // r-quad

        f4 acc[ROWS];
        #pragma unroll
        for (int j = 0; j < ROWS; ++j) acc[j] = (f4)(0.f);

        const float* Ap_base = A + (size_t)(m * NSLOT + s) * (HIDDEN * MAXR);

        #pragma unroll 1
        for (int k = 0; k < 8; ++k) {
            f4 xv[ROWS];
            #pragma unroll
            for (int j = 0; j < ROWS; ++j)
                xv[j] = *(const f4*)(x + (size_t)tok[j] * HIDDEN + 256 * k + 4 * hq);
            const float* Ap = Ap_base + 4096 * k + 64 * hq + 4 * q;
            const f4 a0 = *(const f4*)(Ap);
            const f4 a1 = *(const f4*)(Ap + 16);
            const f4 a2 = *(const f4*)(Ap + 32);
            const f4 a3 = *(const f4*)(Ap + 48);
            #pragma unroll
            for (int j = 0; j < ROWS; ++j) {
                const f4 v = xv[j];
                acc[j] += v.x * a0 + v.y * a1 + v.z * a2 + v.w * a3;
            }
        }

        // butterfly over lane bits 2,3 (low bits of hq)
        #pragma unroll
        for (int j = 0; j < ROWS; ++j) {
            f4 a = acc[j];
            a.x += __shfl_xor(a.x, 4); a.y += __shfl_xor(a.y, 4);
            a.z += __shfl_xor(a.z, 4); a.w += __shfl_xor(a.w, 4);
            a.x += __shfl_xor(a.x, 8); a.y += __shfl_xor(a.y, 8);
            a.z += __shfl_xor(a.z, 8); a.w += __shfl_xor(a.w, 8);
            acc[j] = a;
        }

        if ((t & 12) == 0) {               // lanes 0-3 of each 16-group
            const int w = t >> 6, g = (t >> 4) & 3;
            #pragma unroll
            for (int j = 0; j < ROWS; ++j)
                *(f4*)(red + ((w * 4 + g) * ROWS + j) * MAXR + 4 * q) = acc[j];
        }
        __syncthreads();

        if (t < 128) {   // one (j, r) per thread; sum 16 partials; rank-mask
            const int j = t >> 4, r = t & 15;
            float v = 0.f;
            #pragma unroll
            for (int w = 0; w < 4; ++w)
                #pragma unroll
                for (int g = 0; g < 4; ++g)
                    v += red[((w * 4 + g) * ROWS + j) * MAXR + r];
            if (r >= R) v = 0.f;           // rank mask -> expand needs no mask
            inter[((size_t)m * BS + (i0 + j)) * MAXR + r] = v;
        }
        __syncthreads();                     // red reused next rep
        __asm__ volatile("" ::: "memory");   // no cross-rep CSE/DSE
    }
}

// ---------------------------------------------------------------------------
// Kernel 2: expand — r9 version, 1x (proven at the ~44 us store floor).
// breg[16] cached once per block; uniform inter loads; coalesced float4
// stores; 32-row chunks, grid 2048.
// ---------------------------------------------------------------------------
__global__ __launch_bounds__(256) void lora_expand(
    const float* __restrict__ inter,
    const float* __restrict__ B,
    const int*   __restrict__ slot_offsets,
    const int*   __restrict__ slot_counts,
    float*       __restrict__ out)
{
    int b = blockIdx.x;
    const int rc = b & 15; b >>= 4;      // row chunk   (16 x 32 rows)
    const int ct = b & 7;  b >>= 3;      // col tile    (8 x 1024 cols)
    const int s  = b & 7;  const int m = b >> 3;
    const int t  = threadIdx.x;

    const int row0   = slot_offsets[s] + rc * 32;
    const int rowEnd = slot_offsets[s] + slot_counts[s];
    const int rend   = min(row0 + 32, rowEnd);

    const int c0 = ct * 1024 + t * 4;
    const float* Bp = B + ((size_t)m * NSLOT + s) * MAXR * OUTW + c0;

    f4 breg[MAXR];
    #pragma unroll
    for (int rr = 0; rr < MAXR; ++rr)
        breg[rr] = *(const f4*)(Bp + (size_t)rr * OUTW);

    for (int i = row0; i < rend; ++i) {
        const float* ip = inter + ((size_t)m * BS + i) * MAXR;  // block-uniform
        const f4 w0 = *(const f4*)(ip);
        const f4 w1 = *(const f4*)(ip + 4);
        const f4 w2 = *(const f4*)(ip + 8);
        const f4 w3 = *(const f4*)(ip + 12);
        f4 acc = (f4)(0.f);
        acc += w0.x * breg[0]  + w0.y * breg[1]  + w0.z * breg[2]  + w0.w * breg[3];
        acc += w1.x * breg[4]  + w1.y * breg[5]  + w1.z * breg[6]  + w1.w * breg[7];
        acc += w2.x * breg[8]  + w2.y * breg[9]  + w2.z * breg[10] + w2.w * breg[11];
        acc += w3.x * breg[12] + w3.y * breg[13] + w3.z * breg[14] + w3.w * breg[15];
        *(f4*)(out + (size_t)i * (NMOD * OUTW) + (size_t)m * OUTW + c0) = acc;
    }
}

extern "C" void kernel_launch(void* const* d_in, const int* in_sizes, int n_in,
                              void* d_out, int out_size, void* d_ws, size_t ws_size,
                              hipStream_t stream)
{
    const float* x            = (const float*)d_in[0];
    const float* A            = (const float*)d_in[1];
    const float* B            = (const float*)d_in[2];
    const int*   sorted_ids   = (const int*)d_in[3];
    const int*   slot_counts  = (const int*)d_in[4];
    const int*   slot_ranks   = (const int*)d_in[5];
    const int*   slot_offsets = (const int*)d_in[6];
    float*       out          = (float*)d_out;
    float*       inter        = (float*)d_ws;   // NMOD*BS*MAXR*4 = 512 KiB

    hipLaunchKernelGGL(lora_shrink, dim3(BS / ROWS * NMOD), dim3(256), 0, stream,
                       x, A, sorted_ids, slot_ranks, slot_offsets, inter);
    hipLaunchKernelGGL(lora_expand, dim3(NMOD * NSLOT * 8 * 16), dim3(256), 0, stream,
                       inter, B, slot_offsets, slot_counts, out);
}